// Round 5
// baseline (413.445 us; speedup 1.0000x reference)
//
#include <hip/hip_runtime.h>
#include <math.h>

#define BB 8
#define LL 1024
#define DD 768
#define NNs 16
#define RR 48

typedef __attribute__((ext_vector_type(8))) short bf16x8;
typedef __attribute__((ext_vector_type(4))) float f32x4;

__device__ __forceinline__ float silu_f(float v) { return v / (1.0f + __expf(-v)); }

__device__ __forceinline__ short f2bf(float f) {
    union { float f; unsigned u; } v; v.f = f;
    unsigned r = (v.u + 0x7fffu + ((v.u >> 16) & 1u)) >> 16;
    return (short)r;
}

// raw v_exp_f32: computes 2^x (caller pre-folds log2e into the argument)
__device__ __forceinline__ float exp2_fast(float x) {
    float r;
    asm("v_exp_f32 %0, %1" : "=v"(r) : "v"(x));
    return r;
}

__device__ __forceinline__ void async16(const void* g, void* l) {
    __builtin_amdgcn_global_load_lds((const __attribute__((address_space(1))) void*)g,
                                     (__attribute__((address_space(3))) void*)l,
                                     16, 0, 0);
}

// ---------------------------------------------------------------------------
// K0: fp32 -> bf16 weight conversion
// ---------------------------------------------------------------------------
__global__ __launch_bounds__(256) void k_cvt(const float* __restrict__ src,
                                             short* __restrict__ dst, int n4) {
    int i = blockIdx.x * 256 + threadIdx.x;
    if (i < n4) {
        float4 v = ((const float4*)src)[i];
        short4 o = { f2bf(v.x), f2bf(v.y), f2bf(v.z), f2bf(v.w) };
        ((short4*)dst)[i] = o;
    }
}

// ---------------------------------------------------------------------------
// K1: pos embedding (analytic; batch_params/has_velocity provably cancel) +
// residual + RMSNorm. res fp32, hidden bf16.
// ---------------------------------------------------------------------------
__global__ __launch_bounds__(256) void k_pos_rms(const float* __restrict__ x,
                                                 const float* __restrict__ norm_w,
                                                 float* __restrict__ res,
                                                 short* __restrict__ hidb) {
    int row = blockIdx.x;
    int l = row & (LL - 1);
    int d3 = l & 3;
    int w = (l >> 2) & 15;
    int h = l >> 6;
    float coord[3] = { h * (1.0f / 15.0f), w * (1.0f / 15.0f), d3 * (1.0f / 3.0f) };
    const float LOG1E4 = 9.210340371976184f;
    int t = threadIdx.x;
    float r[3];
    float s = 0.0f;
#pragma unroll
    for (int i = 0; i < 3; i++) {
        int j = t + i * 256;
        int c = j >> 8;
        int fp = j & 255;
        int f = fp & 127;
        float omega = __expf(-(f * (1.0f / 128.0f)) * LOG1E4);
        float arg = coord[c] * omega;
        float pv = (fp < 128) ? __sinf(arg) : __cosf(arg);
        float rv = x[(size_t)row * DD + j] + pv;
        r[i] = rv;
        s += rv * rv;
    }
#pragma unroll
    for (int off = 32; off; off >>= 1) s += __shfl_xor(s, off, 64);
    __shared__ float ls[4];
    if ((t & 63) == 0) ls[t >> 6] = s;
    __syncthreads();
    s = ls[0] + ls[1] + ls[2] + ls[3];
    float rs = rsqrtf(s * (1.0f / DD) + 1e-5f);
#pragma unroll
    for (int i = 0; i < 3; i++) {
        int j = t + i * 256;
        res[(size_t)row * DD + j] = r[i];
        hidb[(size_t)row * DD + j] = f2bf(r[i] * rs * norm_w[j]);
    }
}

// ---------------------------------------------------------------------------
// MFMA bf16 GEMM (NT), 128x128 tile, BK=32, 4 waves. AF32: A is fp32 and is
// converted to bf16 during LDS staging (out_proj path); else async16 staging.
// EPI 1 (in_proj): +bias; n<768 -> C0 (b,t,d); n>=768 -> C1 (b,t,d).
// EPI 3 (out_proj): +bias +resid -> C0.
// ---------------------------------------------------------------------------
template <int EPI, bool AF32>
__global__ __launch_bounds__(256) void gemm_mfma(const void* __restrict__ Ap,
                                                 const short* __restrict__ Bw,
                                                 int Kd,
                                                 const float* __restrict__ bias,
                                                 const float* __restrict__ resid,
                                                 float* __restrict__ C0,
                                                 float* __restrict__ C1) {
    __shared__ short As[4096];   // 128 rows x 32 k, fragment-ordered
    __shared__ short Bs[4096];
    int m0 = blockIdx.y * 128;
    int n0 = blockIdx.x * 128;
    int tid = threadIdx.x;
    int lane = tid & 63, wave = tid >> 6;
    int q = lane >> 4, r = lane & 15;
    int wm = wave >> 1, wn = wave & 1;

    const size_t Kb = (size_t)Kd * 2;
    const char* gB0 = (const char*)Bw + (size_t)(n0 + wave * 16 + r) * Kb + q * 16;
    const char* gB1 = gB0 + 64 * Kb;
    char* lB0 = (char*)Bs + wave * 1024;
    char* lB1 = lB0 + 4096;
    const char* gA0 = nullptr; const char* gA1 = nullptr;
    char* lA0 = nullptr; char* lA1 = nullptr;
    if (!AF32) {
        gA0 = (const char*)Ap + (size_t)(m0 + wave * 16 + r) * Kb + q * 16;
        gA1 = gA0 + 64 * Kb;
        lA0 = (char*)As + wave * 1024;
        lA1 = lA0 + 4096;
    }

    f32x4 acc[4][4] = {};

    for (int k0 = 0; k0 < Kd; k0 += 32) {
        if (AF32) {
            const float* Af = (const float*)Ap;
#pragma unroll
            for (int p = 0; p < 2; p++) {
                int m = m0 + (p * 4 + wave) * 16 + r;
                const float* src = Af + (size_t)m * Kd + k0 + q * 8;
                float4 v0 = *(const float4*)src;
                float4 v1 = *(const float4*)(src + 4);
                bf16x8 pk;
                pk[0] = f2bf(v0.x); pk[1] = f2bf(v0.y);
                pk[2] = f2bf(v0.z); pk[3] = f2bf(v0.w);
                pk[4] = f2bf(v1.x); pk[5] = f2bf(v1.y);
                pk[6] = f2bf(v1.z); pk[7] = f2bf(v1.w);
                *(bf16x8*)&As[p * 2048 + wave * 512 + lane * 8] = pk;
            }
        } else {
            async16(gA0, lA0); async16(gA1, lA1);
            gA0 += 64; gA1 += 64;
        }
        async16(gB0, lB0); async16(gB1, lB1);
        gB0 += 64; gB1 += 64;
        __syncthreads();
        bf16x8 af[4], bf[4];
#pragma unroll
        for (int a = 0; a < 4; a++)
            af[a] = *(const bf16x8*)&As[((wm * 4 + a) * 64 + q * 16 + r) * 8];
#pragma unroll
        for (int b = 0; b < 4; b++)
            bf[b] = *(const bf16x8*)&Bs[((wn * 4 + b) * 64 + q * 16 + r) * 8];
#pragma unroll
        for (int a = 0; a < 4; a++)
#pragma unroll
            for (int b = 0; b < 4; b++)
                acc[a][b] = __builtin_amdgcn_mfma_f32_16x16x32_bf16(
                    af[a], bf[b], acc[a][b], 0, 0, 0);
        __syncthreads();
    }

    // C/D layout: col(n) = lane&15, row(m) = (lane>>4)*4 + reg  [m89/m91]
#pragma unroll
    for (int a = 0; a < 4; a++) {
        int mrow = m0 + (wm * 4 + a) * 16 + q * 4;
#pragma unroll
        for (int b = 0; b < 4; b++) {
            int ncol = n0 + (wn * 4 + b) * 16 + r;
            float bb = bias[ncol];
            if (EPI == 1) {
                float* dst = (ncol < DD) ? (C0 + (size_t)mrow * DD + ncol)
                                         : (C1 + (size_t)mrow * DD + (ncol - DD));
#pragma unroll
                for (int e = 0; e < 4; e++)
                    dst[(size_t)e * DD] = acc[a][b][e] + bb;
            } else {
#pragma unroll
                for (int e = 0; e < 4; e++) {
                    size_t idx = (size_t)(mrow + e) * DD + ncol;
                    C0[idx] = acc[a][b][e] + bb + resid[idx];
                }
            }
        }
    }
}

// ---------------------------------------------------------------------------
// fp32 GEMM. MODE 0 (x_proj): A is xcT in (b,d,t) layout -> TN staging;
// plain store with n<N guard.
// MODE 2 (dt_proj): A row-major; softplus; TRANSPOSED store to (b,d,t).
// ---------------------------------------------------------------------------
template <int MODE>
__global__ __launch_bounds__(256) void gemm_nt(const float* __restrict__ A, int lda,
                                               const float* __restrict__ Bw, int ldb,
                                               int N, int Kd,
                                               const float* __restrict__ bias,
                                               float* __restrict__ C0, int ldc) {
    __shared__ __align__(16) float As[16][68];
    __shared__ __align__(16) float Bs[16][68];
    int m0 = blockIdx.y * 64;
    int n0 = blockIdx.x * 64;
    int t = threadIdx.x;
    int tx = t & 15, ty = t >> 4;
    int ar = t >> 2;
    int ak = (t & 3) * 4;
    int bA = m0 >> 10;           // batch (m within one b: 64 | 1024)
    int t0A = m0 & 1023;
    float acc[4][4] = {};
    for (int k0 = 0; k0 < Kd; k0 += 16) {
        if (MODE == 0) {
            // A = xcT (b,d,t): load float4 over t, store As[k][m] directly
            int kr = t >> 4;       // 0..15
            int am = (t & 15) * 4; // 0..60
            float4 av = *(const float4*)&A[((size_t)(bA * DD) + k0 + kr) * LL + t0A + am];
            *(float4*)&As[kr][am] = av;
        } else {
            float4 av = *(const float4*)(A + (size_t)(m0 + ar) * lda + k0 + ak);
            As[ak + 0][ar] = av.x; As[ak + 1][ar] = av.y;
            As[ak + 2][ar] = av.z; As[ak + 3][ar] = av.w;
        }
        int brow = n0 + ar;
        if (brow >= N) brow = N - 1;
        float4 bv = *(const float4*)(Bw + (size_t)brow * ldb + k0 + ak);
        Bs[ak + 0][ar] = bv.x; Bs[ak + 1][ar] = bv.y;
        Bs[ak + 2][ar] = bv.z; Bs[ak + 3][ar] = bv.w;
        __syncthreads();
#pragma unroll
        for (int kk = 0; kk < 16; kk++) {
            float4 a4 = *(const float4*)&As[kk][ty * 4];
            float4 b4 = *(const float4*)&Bs[kk][tx * 4];
            float aa[4] = { a4.x, a4.y, a4.z, a4.w };
            float bb[4] = { b4.x, b4.y, b4.z, b4.w };
#pragma unroll
            for (int i = 0; i < 4; i++)
#pragma unroll
                for (int j = 0; j < 4; j++) acc[i][j] += aa[i] * bb[j];
        }
        __syncthreads();
    }
    if (MODE == 0) {
#pragma unroll
        for (int i = 0; i < 4; i++) {
            int m = m0 + ty * 4 + i;
#pragma unroll
            for (int j = 0; j < 4; j++) {
                int n = n0 + tx * 4 + j;
                if (n < N) C0[(size_t)m * ldc + n] = acc[i][j];
            }
        }
    } else {
        // softplus + bias, store transposed (b,d,t): per j a float4 over m(=t)
        float4 bi = *(const float4*)(bias + n0 + tx * 4);
        float bl[4] = { bi.x, bi.y, bi.z, bi.w };
        float vv[4][4];
#pragma unroll
        for (int i = 0; i < 4; i++)
#pragma unroll
            for (int j = 0; j < 4; j++) {
                float u = acc[i][j] + bl[j];
                vv[i][j] = (u > 20.0f) ? u : log1pf(__expf(u));
            }
        int tt0 = t0A + ty * 4;
#pragma unroll
        for (int j = 0; j < 4; j++) {
            int dcol = n0 + tx * 4 + j;
            float4 o = { vv[0][j], vv[1][j], vv[2][j], vv[3][j] };
            *(float4*)(C0 + ((size_t)(bA * DD) + dcol) * LL + tt0) = o;
        }
    }
}

// ---------------------------------------------------------------------------
// K3: depthwise causal conv (K=4) + bias + silu.
// Reads xin (b,t,d) coalesced, LDS-transposes, writes xcT (b,d,t) coalesced.
// Block: 64 d x 64 t; grid (12, 16, 8).
// ---------------------------------------------------------------------------
__global__ __launch_bounds__(256) void k_conv(const float* __restrict__ xin,
                                              const float* __restrict__ cw,
                                              const float* __restrict__ cb,
                                              float* __restrict__ xcT) {
    __shared__ float xs[67][65];           // [t row (t0-3..t0+63)][d], pad 65
    int d0 = blockIdx.x * 64;
    int t0 = blockIdx.y * 64;
    int b  = blockIdx.z;
    int tid = threadIdx.x;
    for (int idx = tid; idx < 67 * 16; idx += 256) {
        int row = idx >> 4, c4 = (idx & 15) * 4;
        int t = t0 - 3 + row;
        float4 v = { 0.f, 0.f, 0.f, 0.f };
        if (t >= 0) v = *(const float4*)&xin[((size_t)(b * LL + t)) * DD + d0 + c4];
        xs[row][c4 + 0] = v.x; xs[row][c4 + 1] = v.y;
        xs[row][c4 + 2] = v.z; xs[row][c4 + 3] = v.w;
    }
    __syncthreads();
    int dl = tid >> 2;                     // 0..63
    int ts = (tid & 3) * 16;               // t-segment start
    int d = d0 + dl;
    float4 w = ((const float4*)cw)[d];
    float bias = cb[d];
    float x0 = xs[ts + 0][dl], x1 = xs[ts + 1][dl], x2 = xs[ts + 2][dl];
    float* outp = xcT + ((size_t)(b * DD + d)) * LL + t0 + ts;
    float o0, o1, o2, o3;
#pragma unroll
    for (int i = 0; i < 16; i++) {
        float x3 = xs[ts + i + 3][dl];
        float a = silu_f(bias + x0 * w.x + x1 * w.y + x2 * w.z + x3 * w.w);
        if ((i & 3) == 0) o0 = a;
        else if ((i & 3) == 1) o1 = a;
        else if ((i & 3) == 2) o2 = a;
        else {
            o3 = a;
            float4 o = { o0, o1, o2, o3 };
            *(float4*)(outp + i - 3) = o;
        }
        x0 = x1; x1 = x2; x2 = x3;
    }
}

// ---------------------------------------------------------------------------
// K5: register-state chunked selective scan, v7.
// Partition: 32 chunks x 32 t, 8 d/block (known-good v4). Grid = 96 d-tiles
// x 8 b = 768 blocks = 3/CU, LDS 32 KB, XCD swizzle 12 d-tiles/XCD.
// v7: dt and xc now live TRANSPOSED (b,d,t) -> each thread's 32-t run is
// CONTIGUOUS: one f32x4 load per 4 iterations per stream (was 1 strided
// dword/iter; 4x fewer dependent-load stalls; same per-lane-16B pattern GEMM
// staging sustains at ~6 TB/s). Groups of 4 t, 1-group-ahead prefetch.
// z stays (b,t,d) (strided, 4-batched prefetch); y written in-place strided
// (writes don't stall). exp via pre-scaled log2 + raw v_exp_f32 (v6).
// ---------------------------------------------------------------------------
__global__ __launch_bounds__(256, 3) void k_scan(const float* __restrict__ dtT,
                                                 const float* __restrict__ xcT,
                                                 const float* __restrict__ xdbl,
                                                 const float* __restrict__ A_log,
                                                 const float* __restrict__ Dp,
                                                 float* __restrict__ zy) {
    __shared__ float Pl[32 * 8 * 16];      // [c][d][n] 16 KB; becomes H
    __shared__ float Sl[32 * 8 * 16];      // 16 KB
    int bid = blockIdx.x;
    int xcd = bid & 7;                     // dispatch round-robins bid % 8
    int v = bid >> 3;                      // 0..95 within XCD
    int dtile = xcd * 12 + (v % 12);       // 12 contiguous d-tiles per XCD
    int b = v / 12;
    int d0 = dtile * 8;
    int tid = threadIdx.x;
    int dl = tid & 7;
    int c = tid >> 3;                      // chunk 0..31 (32 t each)
    int d = d0 + dl;

    const float LOG2E = 1.4426950408889634f;
    float Ac[16];
    {
        const float4* al = (const float4*)(A_log + d * NNs);
#pragma unroll
        for (int i = 0; i < 4; i++) {
            float4 v4 = al[i];
            Ac[i * 4 + 0] = -__expf(v4.x) * LOG2E;
            Ac[i * 4 + 1] = -__expf(v4.y) * LOG2E;
            Ac[i * 4 + 2] = -__expf(v4.z) * LOG2E;
            Ac[i * 4 + 3] = -__expf(v4.w) * LOG2E;
        }
    }
    size_t tb = ((size_t)(b * DD + d)) * LL + c * 32;      // transposed base
    const float* dtp = dtT + tb;
    const float* xcp = xcT + tb;
    size_t rb = ((size_t)(b * LL + c * 32)) * DD + d;      // (b,t,d) base
    float* zp = zy + rb;
    const float* xrow = xdbl + ((size_t)(b * LL + c * 32)) * 80 + RR;

    // ---- Phase 1: local scan from zero state; 4-t groups, 1-group prefetch
    float P[16], S[16];
#pragma unroll
    for (int n = 0; n < 16; n++) { P[n] = 1.0f; S[n] = 0.0f; }
    {
        f32x4 dtA = *(const f32x4*)dtp;
        f32x4 xcA = *(const f32x4*)xcp;
        for (int g = 0; g < 8; g++) {
            int off = (g < 7) ? (g * 4 + 4) : (g * 4);
            f32x4 dtN = *(const f32x4*)(dtp + off);
            f32x4 xcN = *(const f32x4*)(xcp + off);
#pragma unroll
            for (int u = 0; u < 4; u++) {
                float dtv = dtA[u], xcv = xcA[u];
                float dx = dtv * xcv;
                const float* Br = xrow + (g * 4 + u) * 80;
#pragma unroll
                for (int qq = 0; qq < 4; qq++) {
                    float4 B4 = *(const float4*)(Br + qq * 4);
                    float bl[4] = { B4.x, B4.y, B4.z, B4.w };
#pragma unroll
                    for (int j = 0; j < 4; j++) {
                        int n = qq * 4 + j;
                        float e = exp2_fast(dtv * Ac[n]);
                        P[n] *= e;
                        S[n] = e * S[n] + dx * bl[j];
                    }
                }
            }
            dtA = dtN; xcA = xcN;
        }
    }
    {
        float* pw = &Pl[(c * 8 + dl) * 16];
        float* sw = &Sl[(c * 8 + dl) * 16];
#pragma unroll
        for (int qq = 0; qq < 4; qq++) {
            float4 pv = { P[qq * 4], P[qq * 4 + 1], P[qq * 4 + 2], P[qq * 4 + 3] };
            float4 sv = { S[qq * 4], S[qq * 4 + 1], S[qq * 4 + 2], S[qq * 4 + 3] };
            *(float4*)(pw + qq * 4) = pv;
            *(float4*)(sw + qq * 4) = sv;
        }
    }
    __syncthreads();
    // ---- Phase 2: serial combine, thread per (d,n); H overwrites Pl
    if (tid < 128) {
        int d2 = tid >> 4, n2 = tid & 15;
        float hh = 0.0f;
#pragma unroll
        for (int cc = 0; cc < 32; cc++) {
            int idx = (cc * 8 + d2) * 16 + n2;
            float Pv = Pl[idx], Sv = Sl[idx];
            Pl[idx] = hh;
            hh = Pv * hh + Sv;
        }
    }
    __syncthreads();
    float h[16];
    {
        const float* hr = &Pl[(c * 8 + dl) * 16];
#pragma unroll
        for (int qq = 0; qq < 4; qq++) {
            float4 v4 = *(const float4*)(hr + qq * 4);
            h[qq * 4] = v4.x; h[qq * 4 + 1] = v4.y;
            h[qq * 4 + 2] = v4.z; h[qq * 4 + 3] = v4.w;
        }
    }
    float Dv = Dp[d];
    // ---- Phase 3: rescan from h_in, gate, write in place (strided, no stall)
    {
        f32x4 dtA = *(const f32x4*)dtp;
        f32x4 xcA = *(const f32x4*)xcp;
        float zA0 = zp[0], zA1 = zp[DD], zA2 = zp[2 * DD], zA3 = zp[3 * DD];
        for (int g = 0; g < 8; g++) {
            int off = (g < 7) ? (g * 4 + 4) : (g * 4);
            f32x4 dtN = *(const f32x4*)(dtp + off);
            f32x4 xcN = *(const f32x4*)(xcp + off);
            float zN0 = zp[(size_t)(off + 0) * DD];
            float zN1 = zp[(size_t)(off + 1) * DD];
            float zN2 = zp[(size_t)(off + 2) * DD];
            float zN3 = zp[(size_t)(off + 3) * DD];
#pragma unroll
            for (int u = 0; u < 4; u++) {
                int i = g * 4 + u;
                float dtv = dtA[u], xcv = xcA[u];
                float zv = (u == 0) ? zA0 : (u == 1) ? zA1 : (u == 2) ? zA2 : zA3;
                float dx = dtv * xcv;
                float y = Dv * xcv;
                const float* Br = xrow + i * 80;
#pragma unroll
                for (int qq = 0; qq < 4; qq++) {
                    float4 B4 = *(const float4*)(Br + qq * 4);
                    float4 C4 = *(const float4*)(Br + 16 + qq * 4);
                    float bl[4] = { B4.x, B4.y, B4.z, B4.w };
                    float cl[4] = { C4.x, C4.y, C4.z, C4.w };
#pragma unroll
                    for (int j = 0; j < 4; j++) {
                        int n = qq * 4 + j;
                        float e = exp2_fast(dtv * Ac[n]);
                        h[n] = e * h[n] + dx * bl[j];
                        y += h[n] * cl[j];
                    }
                }
                zp[(size_t)i * DD] = y * silu_f(zv);
            }
            dtA = dtN; xcA = xcN;
            zA0 = zN0; zA1 = zN1; zA2 = zN2; zA3 = zN3;
        }
    }
}

// ---------------------------------------------------------------------------
extern "C" void kernel_launch(void* const* d_in, const int* in_sizes, int n_in,
                              void* d_out, int out_size, void* d_ws, size_t ws_size,
                              hipStream_t stream) {
    const float* x      = (const float*)d_in[0];
    // d_in[1] batch_params, d_in[2] has_velocity: provably no effect
    const float* norm_w = (const float*)d_in[3];
    const float* in_w   = (const float*)d_in[4];
    const float* in_b   = (const float*)d_in[5];
    const float* conv_w = (const float*)d_in[6];
    const float* conv_b = (const float*)d_in[7];
    const float* xp_w   = (const float*)d_in[8];
    const float* dt_w   = (const float*)d_in[9];
    const float* dt_b   = (const float*)d_in[10];
    const float* A_log  = (const float*)d_in[11];
    const float* Dp     = (const float*)d_in[12];
    const float* out_w  = (const float*)d_in[13];
    const float* out_b  = (const float*)d_in[14];
    float* out = (float*)d_out;

    const size_t S = (size_t)BB * LL * DD;     // 6291456
    float* res   = (float*)d_ws;               // residual (fp32)
    float* slotA = res + S;                    // hidb (bf16) then xcT (fp32)
    float* slotB = slotA + S;                  // xin then dtT (fp32)
    float* zf    = slotB + S;                  // z (b,t,d); gated y in place
    float* xdbl  = zf + S;                     // (B*L, 80)
    short* inw_b  = (short*)(xdbl + (size_t)BB * LL * 80);   // 1536x768 bf16
    short* outw_b = inw_b + 1536 * DD;                       // 768x768 bf16

    short* hidb = (short*)slotA;
    float* xcT  = slotA;                       // (b,d,t) transposed
    float* xin  = slotB;
    float* dtT  = slotB;                       // (b,d,t) transposed

    const int M = BB * LL;                     // 8192

    // 0. weight conversions
    k_cvt<<<(1536 * DD / 4 + 255) / 256, 256, 0, stream>>>(in_w, inw_b, 1536 * DD / 4);
    k_cvt<<<(DD * DD / 4 + 255) / 256, 256, 0, stream>>>(out_w, outw_b, DD * DD / 4);

    // 1. pos + residual + rmsnorm (hidden bf16)
    k_pos_rms<<<M, 256, 0, stream>>>(x, norm_w, res, hidb);

    // 2. in_proj (MFMA): -> xin (b,t,d) | zf (b,t,d)
    gemm_mfma<1, false><<<dim3(1536 / 128, M / 128), 256, 0, stream>>>(
        hidb, inw_b, DD, in_b, nullptr, xin, zf);

    // 3. depthwise conv + silu: xin (b,t,d) -> xcT (b,d,t) (reuses slotA)
    k_conv<<<dim3(DD / 64, LL / 64, BB), 256, 0, stream>>>(xin, conv_w, conv_b, xcT);

    // 4. x_proj: xdbl = xc @ xp_w^T (A read TN from xcT)
    gemm_nt<0><<<dim3(2, M / 64), 256, 0, stream>>>(
        xcT, DD, xp_w, DD, RR + 2 * NNs, DD, nullptr, xdbl, 80);

    // 5. dt_proj + softplus -> dtT (b,d,t) (reuses slotB; xin dead)
    gemm_nt<2><<<dim3(DD / 64, M / 64), 256, 0, stream>>>(
        xdbl, 80, dt_w, RR, DD, RR, dt_b, dtT, DD);

    // 6. register-state chunked scan + gating (zf -> gated y, in place, fp32)
    k_scan<<<768, 256, 0, stream>>>(dtT, xcT, xdbl, A_log, Dp, zf);

    // 7. out_proj (MFMA, fp32 A cvt-staged) + bias + residual -> d_out
    gemm_mfma<3, true><<<dim3(DD / 128, M / 128), 256, 0, stream>>>(
        zf, outw_b, DD, out_b, res, out, nullptr);
}